// Round 6
// baseline (387.875 us; speedup 1.0000x reference)
//
#include <hip/hip_runtime.h>

// PointPillarScatter: B=4, NX=NY=512, C=64, NUM_CLASSES=16, P=80000.
// Inverse-map gather. Each 4-position group's work is split across two
// half-waves (wave-uniform `half`): half 0 = spatial chunks 0-7 + labels +
// pmean + onehot 0-5; half 1 = spatial chunks 8-15 + onehot 6-15.
// All stores stay 64-lane x 16B = 1KB coalesced, non-temporal.
// 8192 waves (2x R5) to hide gathered pf L3 latency; depth-2 pipeline.

#define NXc   512
#define NXY   (512 * 512)          // 262144 = 2^18
#define BATCH 4
#define NPOS  (BATCH * NXY)        // 1048576
#define NCH   64
#define NCLS  16
#define NQ    (NPOS / 4)           // 262144 float4-groups

// output offsets (float elements)
#define OUT1 (BATCH * NCH * NXY)          // labels_seg
#define OUT2 (OUT1 + NPOS)                // onehot
#define OUT3 (OUT2 + BATCH * NCLS * NXY)  // pointsmean

typedef float vfloat4 __attribute__((ext_vector_type(4)));  // clang-native for NT builtin

__global__ void init_map_kernel(int4* __restrict__ map4) {
    int i = blockIdx.x * blockDim.x + threadIdx.x;   // NPOS/4 threads
    map4[i] = make_int4(-1, -1, -1, -1);
}

__global__ void scatter_map_kernel(const int* __restrict__ vc,
                                   int* __restrict__ map, int P) {
    int p = blockIdx.x * blockDim.x + threadIdx.x;
    if (p >= P) return;
    int c0 = vc[p * 4 + 0];
    int c1 = vc[p * 4 + 1];
    int c2 = vc[p * 4 + 2];
    int c3 = vc[p * 4 + 3];
    int g = c0 * NXY + c1 + c2 * NXc + c3;   // matches reference _flat_index
    map[g] = p;
}

__device__ __forceinline__ void nt_store4(float* addr, float x, float y,
                                          float z, float w) {
    vfloat4 v = {x, y, z, w};
    __builtin_nontemporal_store(v, (vfloat4*)addr);
}

__global__ void __launch_bounds__(256)
gather_out_kernel(const float* __restrict__ pf,     // (P,64)
                  const float* __restrict__ seg,    // (P,1)
                  const float* __restrict__ dgt,    // (NPOS,1), identity coords
                  const float* __restrict__ pmean,  // (P,3)
                  const int*   __restrict__ map,    // (NPOS)
                  float* __restrict__ out) {
    int tid  = blockIdx.x * blockDim.x + threadIdx.x;   // 2*NQ threads
    int q    = blockIdx.x * 128 + (threadIdx.x & 127);  // float4-group id
    int half = threadIdx.x >> 7;                        // wave-uniform
    (void)tid;
    int i0 = q << 2;
    int b  = i0 >> 18;
    int s  = i0 & (NXY - 1);

    int4 m = ((const int4*)map)[q];
    int p0 = m.x, p1 = m.y, p2 = m.z, p3 = m.w;

    const float4 z4 = make_float4(0.f, 0.f, 0.f, 0.f);
    int coff = half << 3;                               // chunk base: 0 or 8
    const float4* r0 = (const float4*)(pf + ((long)p0 << 6)) + coff;
    const float4* r1 = (const float4*)(pf + ((long)p1 << 6)) + coff;
    const float4* r2 = (const float4*)(pf + ((long)p2 << 6)) + coff;
    const float4* r3 = (const float4*)(pf + ((long)p3 << 6)) + coff;

    // pipeline prologue: this half's chunks 0 and 1 in flight
    float4 a0 = z4, a1 = z4, a2 = z4, a3 = z4;
    float4 b0 = z4, b1 = z4, b2 = z4, b3 = z4;
    if (p0 >= 0) a0 = r0[0];
    if (p1 >= 0) a1 = r1[0];
    if (p2 >= 0) a2 = r2[0];
    if (p3 >= 0) a3 = r3[0];
    if (p0 >= 0) b0 = r0[1];
    if (p1 >= 0) b1 = r1[1];
    if (p2 >= 0) b2 = r2[1];
    if (p3 >= 0) b3 = r3[1];

    // ---- labels (both halves compute; issues while pf loads are in flight)
    float4 d = ((const float4*)dgt)[q];
    float l0 = d.x, l1 = d.y, l2 = d.z, l3 = d.w;
    if (p0 >= 0) { float sg = seg[p0]; if (sg != 0.f) l0 = sg; }
    if (p1 >= 0) { float sg = seg[p1]; if (sg != 0.f) l1 = sg; }
    if (p2 >= 0) { float sg = seg[p2]; if (sg != 0.f) l2 = sg; }
    if (p3 >= 0) { float sg = seg[p3]; if (sg != 0.f) l3 = sg; }
    int k0 = (int)l0, k1 = (int)l1, k2 = (int)l2, k3 = (int)l3;

    if (half == 0) {            // wave-uniform branch
        nt_store4(out + OUT1 + (q << 2), l0, l1, l2, l3);

        float* pm = out + OUT3 + b * (3 * NXY) + s;
        #pragma unroll
        for (int c = 0; c < 3; ++c) {
            float v0 = (p0 >= 0) ? pmean[p0 * 3 + c] : 0.f;
            float v1 = (p1 >= 0) ? pmean[p1 * 3 + c] : 0.f;
            float v2 = (p2 >= 0) ? pmean[p2 * 3 + c] : 0.f;
            float v3 = (p3 >= 0) ? pmean[p3 * 3 + c] : 0.f;
            nt_store4(pm + c * NXY, v0, v1, v2, v3);
        }

        float* oh = out + OUT2 + b * (NCLS * NXY) + s;
        #pragma unroll
        for (int c = 0; c < 6; ++c)
            nt_store4(oh + c * NXY, c == k0 ? 1.f : 0.f,
                                    c == k1 ? 1.f : 0.f,
                                    c == k2 ? 1.f : 0.f,
                                    c == k3 ? 1.f : 0.f);
    } else {
        float* oh = out + OUT2 + b * (NCLS * NXY) + s;
        #pragma unroll
        for (int c = 6; c < NCLS; ++c)
            nt_store4(oh + c * NXY, c == k0 ? 1.f : 0.f,
                                    c == k1 ? 1.f : 0.f,
                                    c == k2 ? 1.f : 0.f,
                                    c == k3 ? 1.f : 0.f);
    }

    // ---- spatial_features: this half's 8 chunks, depth-2 pipelined transpose
    {
        float* sp = out + b * (NCH * NXY) + s + (coff << 2) * NXY;
        #pragma unroll
        for (int c4 = 0; c4 < 8; ++c4) {
            float4 c0 = z4, c1 = z4, c2 = z4, c3 = z4;
            if (c4 + 2 < 8) {                  // prefetch chunk c4+2
                if (p0 >= 0) c0 = r0[c4 + 2];
                if (p1 >= 0) c1 = r1[c4 + 2];
                if (p2 >= 0) c2 = r2[c4 + 2];
                if (p3 >= 0) c3 = r3[c4 + 2];
            }
            float* o = sp + (c4 << 2) * NXY;
            nt_store4(o,           a0.x, a1.x, a2.x, a3.x);
            nt_store4(o + NXY,     a0.y, a1.y, a2.y, a3.y);
            nt_store4(o + 2 * NXY, a0.z, a1.z, a2.z, a3.z);
            nt_store4(o + 3 * NXY, a0.w, a1.w, a2.w, a3.w);
            a0 = b0; a1 = b1; a2 = b2; a3 = b3;
            b0 = c0; b1 = c1; b2 = c2; b3 = c3;
        }
    }
}

extern "C" void kernel_launch(void* const* d_in, const int* in_sizes, int n_in,
                              void* d_out, int out_size, void* d_ws, size_t ws_size,
                              hipStream_t stream) {
    const float* pf    = (const float*)d_in[0];   // pillar_features (P,64)
    const int*   vc    = (const int*)d_in[1];     // voxel_coords (P,4)
    const float* seg   = (const float*)d_in[2];   // pillar_seg_gt (P,1)
    const float* dgt   = (const float*)d_in[3];   // pillar_dense_gt (NPOS,1)
    // d_in[4] dense_pillar_coords: identity permutation by construction — unused
    const float* pmean = (const float*)d_in[5];   // points_mean (P,3)
    float* out = (float*)d_out;
    int*   map = (int*)d_ws;                      // 4 MB inverse map
    int P = in_sizes[0] / NCH;

    init_map_kernel<<<NPOS / 4 / 256, 256, 0, stream>>>((int4*)map);
    scatter_map_kernel<<<(P + 255) / 256, 256, 0, stream>>>(vc, map, P);
    gather_out_kernel<<<2 * NQ / 256, 256, 0, stream>>>(pf, seg, dgt, pmean, map, out);
}

// Round 7
// 382.591 us; speedup vs baseline: 1.0138x; 1.0138x over previous
//
#include <hip/hip_runtime.h>

// PointPillarScatter: B=4, NX=NY=512, C=64, NUM_CLASSES=16, P=80000.
// FINAL (R5 structure, best measured 384.4us):
// Inverse-map gather, 4 positions/thread, float4 non-temporal stores,
// depth-2 software pipeline on the gathered pf row loads.
// Measured decomposition: harness poison-fill of d_out+d_ws (1.41GB,
// ~220us @6.4TB/s) + input restores sit inside every timed iteration
// (~305-310us fixed); gather itself ~75us vs ~60us traffic floor
// (352MB writes + ~30MB reads). R6's 2x-TLP split-wave variant was
// neutral-negative => gather is store-BW-bound, not latency-bound.

#define NXc   512
#define NXY   (512 * 512)          // 262144 = 2^18
#define BATCH 4
#define NPOS  (BATCH * NXY)        // 1048576
#define NCH   64
#define NCLS  16
#define NQ    (NPOS / 4)           // 262144 float4-groups

// output offsets (float elements)
#define OUT1 (BATCH * NCH * NXY)          // labels_seg
#define OUT2 (OUT1 + NPOS)                // onehot
#define OUT3 (OUT2 + BATCH * NCLS * NXY)  // pointsmean

typedef float vfloat4 __attribute__((ext_vector_type(4)));  // clang-native for NT builtin

__global__ void init_map_kernel(int4* __restrict__ map4) {
    int i = blockIdx.x * blockDim.x + threadIdx.x;   // NPOS/4 threads
    map4[i] = make_int4(-1, -1, -1, -1);
}

__global__ void scatter_map_kernel(const int* __restrict__ vc,
                                   int* __restrict__ map, int P) {
    int p = blockIdx.x * blockDim.x + threadIdx.x;
    if (p >= P) return;
    int c0 = vc[p * 4 + 0];
    int c1 = vc[p * 4 + 1];
    int c2 = vc[p * 4 + 2];
    int c3 = vc[p * 4 + 3];
    int g = c0 * NXY + c1 + c2 * NXc + c3;   // matches reference _flat_index
    map[g] = p;
}

__device__ __forceinline__ void nt_store4(float* addr, float x, float y,
                                          float z, float w) {
    vfloat4 v = {x, y, z, w};
    __builtin_nontemporal_store(v, (vfloat4*)addr);
}

__global__ void __launch_bounds__(256)
gather_out_kernel(const float* __restrict__ pf,     // (P,64)
                  const float* __restrict__ seg,    // (P,1)
                  const float* __restrict__ dgt,    // (NPOS,1), identity coords
                  const float* __restrict__ pmean,  // (P,3)
                  const int*   __restrict__ map,    // (NPOS)
                  float* __restrict__ out) {
    int q  = blockIdx.x * blockDim.x + threadIdx.x;  // NQ threads
    int i0 = q << 2;
    int b  = i0 >> 18;
    int s  = i0 & (NXY - 1);

    int4 m = ((const int4*)map)[q];
    int p0 = m.x, p1 = m.y, p2 = m.z, p3 = m.w;

    const float4 z4 = make_float4(0.f, 0.f, 0.f, 0.f);
    const float4* r0 = (const float4*)(pf + ((long)p0 << 6));
    const float4* r1 = (const float4*)(pf + ((long)p1 << 6));
    const float4* r2 = (const float4*)(pf + ((long)p2 << 6));
    const float4* r3 = (const float4*)(pf + ((long)p3 << 6));

    // pipeline prologue: chunks 0 and 1 in flight
    float4 a0 = z4, a1 = z4, a2 = z4, a3 = z4;
    float4 b0 = z4, b1 = z4, b2 = z4, b3 = z4;
    if (p0 >= 0) a0 = r0[0];
    if (p1 >= 0) a1 = r1[0];
    if (p2 >= 0) a2 = r2[0];
    if (p3 >= 0) a3 = r3[0];
    if (p0 >= 0) b0 = r0[1];
    if (p1 >= 0) b1 = r1[1];
    if (p2 >= 0) b2 = r2[1];
    if (p3 >= 0) b3 = r3[1];

    // ---- labels_seg (issues while pf chunk loads are in flight)
    float4 d = ((const float4*)dgt)[q];
    float l0 = d.x, l1 = d.y, l2 = d.z, l3 = d.w;
    if (p0 >= 0) { float sg = seg[p0]; if (sg != 0.f) l0 = sg; }
    if (p1 >= 0) { float sg = seg[p1]; if (sg != 0.f) l1 = sg; }
    if (p2 >= 0) { float sg = seg[p2]; if (sg != 0.f) l2 = sg; }
    if (p3 >= 0) { float sg = seg[p3]; if (sg != 0.f) l3 = sg; }
    nt_store4(out + OUT1 + (q << 2), l0, l1, l2, l3);

    // ---- onehot (B,16,NY,NX)
    int k0 = (int)l0, k1 = (int)l1, k2 = (int)l2, k3 = (int)l3;
    {
        float* oh = out + OUT2 + b * (NCLS * NXY) + s;
        #pragma unroll
        for (int c = 0; c < NCLS; ++c)
            nt_store4(oh + c * NXY, c == k0 ? 1.f : 0.f,
                                    c == k1 ? 1.f : 0.f,
                                    c == k2 ? 1.f : 0.f,
                                    c == k3 ? 1.f : 0.f);
    }

    // ---- pointsmean (B,3,NY,NX)
    {
        float* pm = out + OUT3 + b * (3 * NXY) + s;
        #pragma unroll
        for (int c = 0; c < 3; ++c) {
            float v0 = (p0 >= 0) ? pmean[p0 * 3 + c] : 0.f;
            float v1 = (p1 >= 0) ? pmean[p1 * 3 + c] : 0.f;
            float v2 = (p2 >= 0) ? pmean[p2 * 3 + c] : 0.f;
            float v3 = (p3 >= 0) ? pmean[p3 * 3 + c] : 0.f;
            nt_store4(pm + c * NXY, v0, v1, v2, v3);
        }
    }

    // ---- spatial_features (B,64,NY,NX): depth-2 pipelined 4x4 transpose
    {
        float* sp = out + b * (NCH * NXY) + s;
        #pragma unroll
        for (int c4 = 0; c4 < NCH / 4; ++c4) {
            float4 c0 = z4, c1 = z4, c2 = z4, c3 = z4;
            if (c4 + 2 < NCH / 4) {            // prefetch chunk c4+2
                if (p0 >= 0) c0 = r0[c4 + 2];
                if (p1 >= 0) c1 = r1[c4 + 2];
                if (p2 >= 0) c2 = r2[c4 + 2];
                if (p3 >= 0) c3 = r3[c4 + 2];
            }
            float* o = sp + (c4 << 2) * NXY;
            nt_store4(o,           a0.x, a1.x, a2.x, a3.x);
            nt_store4(o + NXY,     a0.y, a1.y, a2.y, a3.y);
            nt_store4(o + 2 * NXY, a0.z, a1.z, a2.z, a3.z);
            nt_store4(o + 3 * NXY, a0.w, a1.w, a2.w, a3.w);
            a0 = b0; a1 = b1; a2 = b2; a3 = b3;
            b0 = c0; b1 = c1; b2 = c2; b3 = c3;
        }
    }
}

extern "C" void kernel_launch(void* const* d_in, const int* in_sizes, int n_in,
                              void* d_out, int out_size, void* d_ws, size_t ws_size,
                              hipStream_t stream) {
    const float* pf    = (const float*)d_in[0];   // pillar_features (P,64)
    const int*   vc    = (const int*)d_in[1];     // voxel_coords (P,4)
    const float* seg   = (const float*)d_in[2];   // pillar_seg_gt (P,1)
    const float* dgt   = (const float*)d_in[3];   // pillar_dense_gt (NPOS,1)
    // d_in[4] dense_pillar_coords: identity permutation by construction — unused
    const float* pmean = (const float*)d_in[5];   // points_mean (P,3)
    float* out = (float*)d_out;
    int*   map = (int*)d_ws;                      // 4 MB inverse map
    int P = in_sizes[0] / NCH;

    init_map_kernel<<<NPOS / 4 / 256, 256, 0, stream>>>((int4*)map);
    scatter_map_kernel<<<(P + 255) / 256, 256, 0, stream>>>(vc, map, P);
    gather_out_kernel<<<NQ / 256, 256, 0, stream>>>(pf, seg, dgt, pmean, map, out);
}